// Round 13
// baseline (86.671 us; speedup 1.0000x reference)
//
#include <hip/hip_runtime.h>

// Bit-exact recipe (locked R1-R7, absmax 0.0078 vs 0.106 thr):
//   cube  = (x*x)*x ;  j-sum = T3  ((m0+m4)+m2)+(m1+m3) ;  no fma anywhere
//   coef  = sequential ascending fp32 prod (b==j -> 1.0), IEEE divide
//   i-sum = sequential ascending, unfused mul/add
// Cross-round synthesis: all structures converge to ~32-35us VALU-issue time
// (2.5x the 12.8us @2.4GHz hand count) -> either DVFS ~1GHz during short
// bursts (T-clock) or insufficient TLP/ILP (T-TLP). R12 had only 2 waves/SIMD
// (512 blocks). R13 = R12's staged-copy table at QPT=4 / 1024 blocks =
// 4 blocks/CU = 4 waves/SIMD: clean A/B between the theories.
#pragma clang fp contract(off)

#define FEATURES   512
#define N_BSPLINES 64
#define N_KNOTS    68   // N_BSPLINES + DEGREE + 1
#define WINDOW     5    // DEGREE + 2
#define BATCH      2048

#define TF 16          // features per block (lane low bits -> coalesced)
#define TB 64          // batch rows per block
#define QPT 4          // rows per thread
#define NT 256
#define TSTRIDE 516    // floats per feature row: 64*8 + 4 pad (ft,ft+8 share banks: 2-way, free)

__device__ __forceinline__ float cube_f32(float r) {
    float s = r * r;
    return s * r;
}

// One block per feature; thread t = i*5+j computes coef[i][j]; t<64 also
// writes w and next-knot slots. Bit-exact: sequential ascending fp32
// product (b==j -> exact 1.0), IEEE fp32 divide.
__global__ __launch_bounds__(320) void bspline_prep(
    const float* __restrict__ knots, const float* __restrict__ weights,
    float* __restrict__ g)
{
    const int f = blockIdx.x;
    const int t = threadIdx.x;             // 0..319
    const float* kf = knots + f * N_KNOTS;
    const int i = t / WINDOW, j = t % WINDOW;
    float kj = kf[i + j];
    float prod = 1.0f;
    #pragma unroll
    for (int b = 0; b < WINDOW; ++b) {
        float df = (b == j) ? 1.0f : (kf[i + b] - kj);
        prod = prod * df;
    }
    g[f * TSTRIDE + i * 8 + j] = 1.0f / prod;
    if (t < N_BSPLINES) {
        g[f * TSTRIDE + t * 8 + 5] = weights[f * N_BSPLINES + t];
        g[f * TSTRIDE + t * 8 + 6] = (t < N_BSPLINES - 1) ? kf[t + 5] : 0.0f;
        g[f * TSTRIDE + t * 8 + 7] = 0.0f;
    }
}

// One i-step; window registers passed rotated so retire-and-refill needs no
// v_movs (period-5 unroll). RA retires and is refilled with the new cube.
#define STEP(I, RA, RB, RC, RD, RE)                                         \
    do {                                                                    \
        const float4 cv = *(const float4*)&row[(I) * 8];     /* c0..c3 */   \
        const float4 cw = *(const float4*)&row[(I) * 8 + 4]; /* c4,w,kn */  \
        _Pragma("unroll")                                                   \
        for (int q = 0; q < QPT; ++q) {                                     \
            float m0 = RA[q] * cv.x;                                        \
            float m1 = RB[q] * cv.y;                                        \
            float m2 = RC[q] * cv.z;                                        \
            float m3 = RD[q] * cv.w;                                        \
            float m4 = RE[q] * cw.x;                                        \
            float t04  = m0 + m4;   /* T3: masked-tail fold */              \
            float t042 = t04 + m2;                                          \
            float t13  = m1 + m3;                                           \
            float sp   = t042 + t13;                                        \
            acc[q] = acc[q] + sp * cw.y;  /* unfused sequential i-sum */    \
            RA[q] = cube_f32(fmaxf(xq[q] - cw.z, 0.0f));                    \
        }                                                                   \
    } while (0)

__global__ __launch_bounds__(NT, 4) void bspline_eval(
    const float* __restrict__ x, const float* __restrict__ knots,
    const float* __restrict__ coefg, float* __restrict__ out)
{
    __shared__ float tab[TF * TSTRIDE];

    const int tid  = threadIdx.x;
    const int fblk = blockIdx.x & (FEATURES / TF - 1);   // 0..31
    const int bblk = blockIdx.x >> 5;                    // 0..31
    const int f0   = fblk * TF;
    const int b0   = bblk * TB;
    const int ft   = tid & (TF - 1);
    const int bt   = tid >> 4;             // 0..15

    // Early global loads: x rows and the first 5 knots (overlap staging).
    float xq[QPT];
    #pragma unroll
    for (int q = 0; q < QPT; ++q)
        xq[q] = x[(b0 + bt + q * 16) * FEATURES + f0 + ft];
    const float* kf = knots + (f0 + ft) * N_KNOTS;
    float k0 = kf[0], k1 = kf[1], k2 = kf[2], k3 = kf[3], k4 = kf[4];

    // Stage coef table: global layout for f0..f0+15 == LDS layout -> flat
    // coalesced float4 copy, conflict-free.
    const float4* __restrict__ gsrc = (const float4*)(coefg + (size_t)f0 * TSTRIDE);
    float4* __restrict__ tabv = (float4*)tab;
    for (int e = tid; e < TF * TSTRIDE / 4; e += NT)     // 2064 float4
        tabv[e] = gsrc[e];
    __syncthreads();

    const float* __restrict__ row = &tab[ft * TSTRIDE];

    float acc[QPT], r0[QPT], r1[QPT], r2[QPT], r3[QPT], r4[QPT];
    #pragma unroll
    for (int q = 0; q < QPT; ++q) {
        acc[q] = 0.0f;
        r0[q] = cube_f32(fmaxf(xq[q] - k0, 0.0f));
        r1[q] = cube_f32(fmaxf(xq[q] - k1, 0.0f));
        r2[q] = cube_f32(fmaxf(xq[q] - k2, 0.0f));
        r3[q] = cube_f32(fmaxf(xq[q] - k3, 0.0f));
        r4[q] = cube_f32(fmaxf(xq[q] - k4, 0.0f));
    }

    // 60 steps in groups of 5 (rotation period) + 4 tail steps: zero movs.
    // unroll 2: ds_read lookahead window without I-cache blowup (~600 inst).
    #pragma unroll 2
    for (int gi = 0; gi < 12; ++gi) {
        const int i = gi * 5;
        STEP(i + 0, r0, r1, r2, r3, r4);
        STEP(i + 1, r1, r2, r3, r4, r0);
        STEP(i + 2, r2, r3, r4, r0, r1);
        STEP(i + 3, r3, r4, r0, r1, r2);
        STEP(i + 4, r4, r0, r1, r2, r3);
    }
    STEP(60, r0, r1, r2, r3, r4);
    STEP(61, r1, r2, r3, r4, r0);
    STEP(62, r2, r3, r4, r0, r1);
    STEP(63, r3, r4, r0, r1, r2);          // kn slot = 0.0 -> dead cube

    #pragma unroll
    for (int q = 0; q < QPT; ++q)
        out[(b0 + bt + q * 16) * FEATURES + f0 + ft] = acc[q];
}

extern "C" void kernel_launch(void* const* d_in, const int* in_sizes, int n_in,
                              void* d_out, int out_size, void* d_ws, size_t ws_size,
                              hipStream_t stream) {
    const float* x       = (const float*)d_in[0];   // (2048, 512)
    const float* knots   = (const float*)d_in[1];   // (512, 68)
    const float* weights = (const float*)d_in[2];   // (512, 64)
    float*       out     = (float*)d_out;           // (2048, 512)
    float*       coefg   = (float*)d_ws;            // 512*516 floats ~ 1.01 MB

    bspline_prep<<<FEATURES, 320, 0, stream>>>(knots, weights, coefg);

    const int blocks = (FEATURES / TF) * (BATCH / TB);   // 32 * 32 = 1024
    bspline_eval<<<blocks, NT, 0, stream>>>(x, knots, coefg, out);
}